// Round 13
// baseline (1309.662 us; speedup 1.0000x reference)
//
#include <hip/hip_runtime.h>

#define D128 128
#define NT 101
#define TDEC 512
#define PSTR 112            // padded p row: 4 quarters of 28 floats (16B aligned)
#define PVP 116             // VH inner (n) pitch, mult of 4 -> aligned b128
#define VGPP (16*PVP)       // per-head VH pitch = 1856 floats
#define LGB 832             // one LGH buffer: 8 waves x 104 (b32 conflict-free)

// ---- decode LDS layout (floats) ----
#define VH_OFF   0                       // [8][16 d][PVP n] V slices (n zero-padded)
#define P_OFF    (VH_OFF + 8*VGPP)       // 8 x PSTR
#define LGH_OFF  (P_OFF + 8*PSTR)        // 2 x 8 x 104 double-buffered logit partials
#define QVS_OFF  (LGH_OFF + 2*LGB)       // 8 x 16 per-wave q slices
#define OS_OFF   (QVS_OFF + 128)         // 8 x 16 per-wave o slices
#define LDS_FLOATS (OS_OFF + 128)        // 17664 floats = 70,656 B -> 2 WG/CU

#define INV_D_CONST 0.08838834764831845f
#define NEG_INF __int_as_float(0xff800000)

__device__ __forceinline__ int read_scalar_int(const void* p){
    unsigned u = *(const unsigned*)p;
    if (u < 1000000u) return (int)u;
    return (int)__uint_as_float(u);
}
__device__ __forceinline__ float read_scalar_float(const void* p){
    unsigned u = *(const unsigned*)p;
    if (u < 1000000u) return (float)(int)u;
    return __uint_as_float(u);
}

// ---- DPP cross-lane helpers (VALU pipe, no DS) — verified correct R10/R11/R12 ----
template<int C> __device__ __forceinline__ float dppf(float x){
    return __int_as_float(__builtin_amdgcn_update_dpp(
        __float_as_int(x), __float_as_int(x), C, 0xF, 0xF, false));
}
template<int C> __device__ __forceinline__ int dppi(int x){
    return __builtin_amdgcn_update_dpp(x, x, C, 0xF, 0xF, false);
}
template<int C, int RM> __device__ __forceinline__ float dppmf(float idv, float x){
    return __int_as_float(__builtin_amdgcn_update_dpp(
        __float_as_int(idv), __float_as_int(x), C, RM, 0xF, false));
}
template<int C, int RM> __device__ __forceinline__ int dppmi(int idv, int x){
    return __builtin_amdgcn_update_dpp(idv, x, C, RM, 0xF, false);
}
__device__ __forceinline__ float rdlf(float v, int lane){
    return __int_as_float(__builtin_amdgcn_readlane(__float_as_int(v), lane));
}
// Canonical wave64 reductions: 4 mirror stages (rows uniform), bcast15/31 merge.
__device__ __forceinline__ float wave_sum64(float v){
    v += dppf<0xB1>(v); v += dppf<0x4E>(v); v += dppf<0x141>(v); v += dppf<0x140>(v);
    v += dppmf<0x142,0xa>(0.f, v);
    v += dppmf<0x143,0x8>(0.f, v);
    return rdlf(v, 63);
}
__device__ __forceinline__ float wave_max64(float v){
    v = fmaxf(v, dppf<0xB1>(v)); v = fmaxf(v, dppf<0x4E>(v));
    v = fmaxf(v, dppf<0x141>(v)); v = fmaxf(v, dppf<0x140>(v));
    v = fmaxf(v, dppmf<0x142,0xa>(NEG_INF, v));
    v = fmaxf(v, dppmf<0x143,0x8>(NEG_INF, v));
    return rdlf(v, 63);
}
__device__ __forceinline__ void wave_argmax64(float& v, int& i){
    { float ov = dppf<0xB1>(v);  int oi = dppi<0xB1>(i);  if (ov>v || (ov==v && oi<i)){v=ov;i=oi;} }
    { float ov = dppf<0x4E>(v);  int oi = dppi<0x4E>(i);  if (ov>v || (ov==v && oi<i)){v=ov;i=oi;} }
    { float ov = dppf<0x141>(v); int oi = dppi<0x141>(i); if (ov>v || (ov==v && oi<i)){v=ov;i=oi;} }
    { float ov = dppf<0x140>(v); int oi = dppi<0x140>(i); if (ov>v || (ov==v && oi<i)){v=ov;i=oi;} }
    { float ov = dppmf<0x142,0xa>(NEG_INF, v); int oi = dppmi<0x142,0xa>(0, i);
      if (ov>v || (ov==v && oi<i)){v=ov;i=oi;} }
    { float ov = dppmf<0x143,0x8>(NEG_INF, v); int oi = dppmi<0x143,0x8>(0, i);
      if (ov>v || (ov==v && oi<i)){v=ov;i=oi;} }
    v = rdlf(v, 63);
    i = __builtin_amdgcn_readlane(i, 63);
}

// ---------------- weight folding (unchanged) ----------------
__global__ __launch_bounds__(512) void prep_w2(
        const float* __restrict__ fc_w, const float* __restrict__ attn_w,
        const float* __restrict__ prob_k, const float* __restrict__ attn_fc,
        const float* __restrict__ attn_k, const float* __restrict__ attn_v,
        float* __restrict__ Wcat, float* __restrict__ wlast){
    int i = blockIdx.x, t = threadIdx.x;
    if (i < 128){
        if (t < 128){
            Wcat[i*512 + t] = attn_k[i*D128 + t];
        } else if (t < 256){
            int j = t - 128;
            Wcat[i*512 + 128 + j] = attn_v[i*D128 + j];
        } else if (t < 384){
            int j = t - 256; float acc = 0.f;
            for (int e = 0; e < D128; ++e) acc += prob_k[i*D128+e]*attn_fc[j*D128+e];
            Wcat[i*512 + 256 + j] = acc;
        } else {
            int j = t - 384; float acc = 0.f;
            for (int e = 0; e < D128; ++e) acc += fc_w[i*D128+e]*attn_w[e*D128+j];
            Wcat[i*512 + 384 + j] = acc;
        }
    } else if (t < 128){
        float acc = 0.f;
        for (int e = 0; e < D128; ++e) acc += fc_w[128*D128+e]*attn_w[e*D128+t];
        wlast[t] = acc;
    }
}

__global__ __launch_bounds__(128) void prep_pq(
        const float* __restrict__ pool, const float* __restrict__ fc1_w,
        const float* __restrict__ attn_w, float* __restrict__ pq){
    __shared__ float s1[128], s2[128];
    int b = blockIdx.x, t = threadIdx.x;
    s1[t] = pool[(size_t)b*D128 + t];
    __syncthreads();
    float a = 0.f;
    for (int i = 0; i < D128; ++i) a += s1[i]*fc1_w[i*D128 + t];
    s2[t] = a;
    __syncthreads();
    float a2 = 0.f;
    for (int i = 0; i < D128; ++i) a2 += s2[i]*attn_w[i*D128 + t];
    pq[(size_t)b*D128 + t] = a2;
}

__global__ __launch_bounds__(256) void gemm_prep(
        const float* __restrict__ enc, const float* __restrict__ Wcat,
        const float* __restrict__ pq, int M,
        float* __restrict__ KVP, float* __restrict__ QA){
    __shared__ float As[64*132];
    const int t = threadIdx.x;
    const int m0 = blockIdx.x * 64;
    const int cb0 = blockIdx.y * 64;
    for (int i = t; i < 64*32; i += 256){
        int row = i >> 5, c4 = (i & 31) << 2;
        float4 val = make_float4(0.f,0.f,0.f,0.f);
        if (m0 + row < M) val = *(const float4*)(enc + (size_t)(m0+row)*D128 + c4);
        *(float4*)&As[row*132 + c4] = val;
    }
    __syncthreads();
    const int tx = t & 15, ty = t >> 4;
    float acc[4][4];
    #pragma unroll
    for (int i = 0; i < 4; ++i)
        #pragma unroll
        for (int j = 0; j < 4; ++j) acc[i][j] = 0.f;
    const float* wp = Wcat + cb0 + tx*4;
    #pragma unroll 4
    for (int k = 0; k < 128; ++k){
        float4 bv = *(const float4*)(wp + (size_t)k*512);
        float a0 = As[(ty*4+0)*132 + k];
        float a1 = As[(ty*4+1)*132 + k];
        float a2 = As[(ty*4+2)*132 + k];
        float a3 = As[(ty*4+3)*132 + k];
        acc[0][0] += a0*bv.x; acc[0][1] += a0*bv.y; acc[0][2] += a0*bv.z; acc[0][3] += a0*bv.w;
        acc[1][0] += a1*bv.x; acc[1][1] += a1*bv.y; acc[1][2] += a1*bv.z; acc[1][3] += a1*bv.w;
        acc[2][0] += a2*bv.x; acc[2][1] += a2*bv.y; acc[2][2] += a2*bv.z; acc[2][3] += a2*bv.w;
        acc[3][0] += a3*bv.x; acc[3][1] += a3*bv.y; acc[3][2] += a3*bv.z; acc[3][3] += a3*bv.w;
    }
    #pragma unroll
    for (int rr = 0; rr < 4; ++rr){
        int m = m0 + ty*4 + rr;
        if (m >= M) continue;
        if (cb0 < 384){
            *(float4*)&KVP[(size_t)m*384 + cb0 + tx*4] =
                make_float4(acc[rr][0], acc[rr][1], acc[rr][2], acc[rr][3]);
        } else {
            int bb = m / NT;
            int c = cb0 - 384 + tx*4;
            float4 pv = *(const float4*)(pq + (size_t)bb*D128 + c);
            *(float4*)&QA[(size_t)m*D128 + c] =
                make_float4(acc[rr][0]+pv.x, acc[rr][1]+pv.y, acc[rr][2]+pv.z, acc[rr][3]+pv.w);
        }
    }
}

// ---------------- sequential decode: 8 waves per batch elem, ONE barrier/step ----------------
// R12 structure (VGPR=64, 2 WG/CU, VALU-bound ~90%) + VALU->DS rebalance:
// q and o dot-products read own-wave LDS slices via uniform-address b128 broadcast
// (replaces 2x16 v_readlane); LGH back to conflict-free [w*104+l] b32 layout.
__global__ __attribute__((amdgpu_flat_work_group_size(TDEC, TDEC)))
void decode(
    const float* __restrict__ QA, const float* __restrict__ KVP,
    const float* __restrict__ wlast, const float* __restrict__ demand,
    const float* __restrict__ capv, const void* p_nd, const void* p_temp,
    int n_steps, float* __restrict__ out)
{
    __shared__ float sm[LDS_FLOATS];
    const int b = blockIdx.x, t = threadIdx.x;
    const int l = t & 63, g = t >> 6;          // lane, wave (= head = dim-block)
    const int qq = l >> 4, d16 = l & 15;       // PV mapping
    const int nd = read_scalar_int(p_nd);
    const float temp = read_scalar_float(p_temp);
    const float invtemp = 1.0f / temp;         // host-scalar; logp path only
    const float capfull = capv[0];
    float dyn = capv[b];
    const long mb = (long)b * NT;
    const bool hasB = (l < NT - 64);           // second-row validity (l < 37)

    // ---- K rows (head g) for n = l, l+64 ----
    float k0[16], k1[16];
    {
        const float* kr = KVP + (mb + l)*384 + g*16;
        #pragma unroll
        for (int j4 = 0; j4 < 4; ++j4){
            float4 a = *(const float4*)(kr + j4*4);
            k0[j4*4+0]=a.x; k0[j4*4+1]=a.y; k0[j4*4+2]=a.z; k0[j4*4+3]=a.w;
        }
    }
    if (hasB){
        const float* kr = KVP + (mb + l + 64)*384 + g*16;
        #pragma unroll
        for (int j4 = 0; j4 < 4; ++j4){
            float4 a = *(const float4*)(kr + j4*4);
            k1[j4*4+0]=a.x; k1[j4*4+1]=a.y; k1[j4*4+2]=a.z; k1[j4*4+3]=a.w;
        }
    } else {
        #pragma unroll
        for (int j = 0; j < 16; ++j) k1[j] = 0.f;
    }
    float kwl1 = 0.f, kwl2 = 0.f;
    #pragma unroll
    for (int j = 0; j < 16; ++j){
        float w = wlast[g*16 + j];
        kwl1 += w*k0[j]; kwl2 += w*k1[j];
    }
    // ---- kp2 rows (dims 16g..16g+16) for n = l, l+64 ----
    float p2a[16], p2b[16];
    {
        const float* kr = KVP + (mb + l)*384 + 256 + g*16;
        #pragma unroll
        for (int j4 = 0; j4 < 4; ++j4){
            float4 a = *(const float4*)(kr + j4*4);
            p2a[j4*4+0]=a.x; p2a[j4*4+1]=a.y; p2a[j4*4+2]=a.z; p2a[j4*4+3]=a.w;
        }
    }
    if (hasB){
        const float* kr = KVP + (mb + l + 64)*384 + 256 + g*16;
        #pragma unroll
        for (int j4 = 0; j4 < 4; ++j4){
            float4 a = *(const float4*)(kr + j4*4);
            p2b[j4*4+0]=a.x; p2b[j4*4+1]=a.y; p2b[j4*4+2]=a.z; p2b[j4*4+3]=a.w;
        }
    } else {
        #pragma unroll
        for (int j = 0; j < 16; ++j) p2b[j] = 0.f;
    }
    // ---- demand + mask registers (redundant across waves) ----
    float dem1 = demand[mb + l];
    float dem2 = hasB ? demand[mb + l + 64] : 0.f;
    float mk1a = 0.f, mk1b = 0.f;
    float m1 = (l < nd) ? 1.f : ((dem1 > dyn) ? 1.f : 0.f);
    float m2 = ((l + 64) < nd) ? 1.f : ((dem2 > dyn) ? 1.f : 0.f);
    int served = 0; float logps = 0.f;

    // ---- stage VH[g][d][n] transposed (n zero-padded to PVP), P pads ----
    for (int i = t; i < 8*112*16; i += TDEC){
        int gg = i / 1792, r = i - gg*1792;
        int n = r >> 4, d = r & 15;            // d inner: coalesced global read
        sm[VH_OFF + gg*VGPP + d*PVP + n] =
            (n < NT) ? KVP[(mb + n)*384 + 128 + gg*16 + d] : 0.f;
    }
    for (int i = t; i < 8*PSTR; i += TDEC) sm[P_OFF + i] = 0.f;
    // initial q slice (index0 = 0): own-wave QVS slice
    if (l < 16) sm[QVS_OFF + g*16 + l] = QA[mb*D128 + g*16 + l];
    __syncthreads();

    for (int s = 0; s < n_steps; ++s){
        // ==== P1: q via uniform-address broadcast reads (own-wave slice) ====
        float qk1, qk2;
        {
            const float4* qp = (const float4*)&sm[QVS_OFF + g*16];
            float4 qA = qp[0], qB = qp[1], qC = qp[2], qD = qp[3];
            qk1  = qA.x*k0[0];  qk2  = qA.x*k1[0];
            qk1 += qA.y*k0[1];  qk2 += qA.y*k1[1];
            qk1 += qA.z*k0[2];  qk2 += qA.z*k1[2];
            qk1 += qA.w*k0[3];  qk2 += qA.w*k1[3];
            qk1 += qB.x*k0[4];  qk2 += qB.x*k1[4];
            qk1 += qB.y*k0[5];  qk2 += qB.y*k1[5];
            qk1 += qB.z*k0[6];  qk2 += qB.z*k1[6];
            qk1 += qB.w*k0[7];  qk2 += qB.w*k1[7];
            qk1 += qC.x*k0[8];  qk2 += qC.x*k1[8];
            qk1 += qC.y*k0[9];  qk2 += qC.y*k1[9];
            qk1 += qC.z*k0[10]; qk2 += qC.z*k1[10];
            qk1 += qC.w*k0[11]; qk2 += qC.w*k1[11];
            qk1 += qD.x*k0[12]; qk2 += qD.x*k1[12];
            qk1 += qD.y*k0[13]; qk2 += qD.y*k1[13];
            qk1 += qD.z*k0[14]; qk2 += qD.z*k1[14];
            qk1 += qD.w*k0[15]; qk2 += qD.w*k1[15];
        }
        float c1 = 0.25f*(qk1 + dyn*kwl1);
        if (m1 > 0.f) c1 = -1000000000.0f;
        float c2 = -1000000000.0f;
        if (hasB){
            float a = 0.25f*(qk2 + dyn*kwl2);
            c2 = (m2 > 0.f) ? -1000000000.0f : a;
        }
        float mx = wave_max64(fmaxf(c1, c2));
        float p1 = __expf(c1 - mx);
        float p2v = hasB ? __expf(c2 - mx) : 0.f;
        float ls = wave_sum64(p1 + p2v);
        sm[P_OFF + g*PSTR + l] = p1;
        if (hasB) sm[P_OFF + g*PSTR + 64 + l] = p2v;
        // same-wave DS ordering: write->read needs no __syncthreads
        float acc = 0.f;
        {
            const float4* pp = (const float4*)&sm[P_OFF + g*PSTR + qq*28];
            const float4* vp = (const float4*)&sm[VH_OFF + g*VGPP + d16*PVP + qq*28];
            #pragma unroll
            for (int i4 = 0; i4 < 7; ++i4){
                float4 pv = pp[i4];
                float4 vv = vp[i4];
                acc += pv.x*vv.x + pv.y*vv.y + pv.z*vv.z + pv.w*vv.w;
            }
        }
        // butterfly: every lane ends with the full sum for its d16 column
        acc += __shfl_xor(acc, 16, 64);
        acc += __shfl_xor(acc, 32, 64);
        // ls is wave-uniform: Newton-refined reciprocal, 1 mul per lane
        float lr = __builtin_amdgcn_rcpf(ls);
        lr = lr * (2.0f - ls*lr);
        if (l < 16) sm[OS_OFF + g*16 + l] = acc * lr;   // own-wave o slice

        // ==== P2: o via uniform-address broadcast reads (own-wave slice) ====
        float lg1, lg2;
        {
            const float4* op = (const float4*)&sm[OS_OFF + g*16];
            float4 oA = op[0], oB = op[1], oC = op[2], oD = op[3];
            lg1  = oA.x*p2a[0];  lg2  = oA.x*p2b[0];
            lg1 += oA.y*p2a[1];  lg2 += oA.y*p2b[1];
            lg1 += oA.z*p2a[2];  lg2 += oA.z*p2b[2];
            lg1 += oA.w*p2a[3];  lg2 += oA.w*p2b[3];
            lg1 += oB.x*p2a[4];  lg2 += oB.x*p2b[4];
            lg1 += oB.y*p2a[5];  lg2 += oB.y*p2b[5];
            lg1 += oB.z*p2a[6];  lg2 += oB.z*p2b[6];
            lg1 += oB.w*p2a[7];  lg2 += oB.w*p2b[7];
            lg1 += oC.x*p2a[8];  lg2 += oC.x*p2b[8];
            lg1 += oC.y*p2a[9];  lg2 += oC.y*p2b[9];
            lg1 += oC.z*p2a[10]; lg2 += oC.z*p2b[10];
            lg1 += oC.w*p2a[11]; lg2 += oC.w*p2b[11];
            lg1 += oD.x*p2a[12]; lg2 += oD.x*p2b[12];
            lg1 += oD.y*p2a[13]; lg2 += oD.y*p2b[13];
            lg1 += oD.z*p2a[14]; lg2 += oD.z*p2b[14];
            lg1 += oD.w*p2a[15]; lg2 += oD.w*p2b[15];
        }
        {
            float* lgp = &sm[LGH_OFF + (s & 1)*LGB + g*104];
            lgp[l] = lg1;
            if (hasB) lgp[64 + l] = lg2;
        }
        __syncthreads();                       // the ONE barrier per step

        // ==== F: redundant in every wave (each needs bix for its own q fetch) ====
        const float* lgb = &sm[LGH_OFF + (s & 1)*LGB];
        float s1v = 0.f;
        #pragma unroll
        for (int w = 0; w < 8; ++w) s1v += lgb[w*104 + l];
        float s2v = 0.f;
        if (hasB){
            #pragma unroll
            for (int w = 0; w < 8; ++w) s2v += lgb[w*104 + 64 + l];
        }
        float r1 = (m1 > 0.f) ? -3.0e38f : s1v;
        float r2 = hasB ? ((m2 > 0.f) ? -3.0e38f : s2v) : -3.3e38f;
        float bv = r1; int bix = l;
        if (r2 > bv){ bv = r2; bix = l + 64; }
        wave_argmax64(bv, bix);
        // next q slice: global load -> own-wave QVS write (read next step, in-order)
        if (l < 16) sm[QVS_OFF + g*16 + l] = QA[(mb + bix)*D128 + g*16 + l];
        // save pre-update state for wave0's shadow lse
        float m1o = m1, m2o = m2;
        bool keep_lp = (served < NT - 1);
        // bookkeeping (wave-uniform; readlane, no DS)
        float selv = (bix < 64) ? rdlf(dem1, bix) : rdlf(dem2, bix - 64);
        float vis  = (bix < 64) ? rdlf(mk1a, bix) : rdlf(mk1b, bix - 64);
        bool go = bix < nd;
        float dynN = go ? capfull : (dyn - selv);
        if (!go && vis == 0.f) served++;
        if (bix == l && l >= nd) mk1a = 1.f;
        if (hasB && bix == (l + 64)) mk1b = 1.f;
        bool done = served >= NT - nd;
        float depotf = (go && !done) ? 1.f : 0.f;
        dyn = dynN;
        m1 = fmaxf(mk1a, (dem1 > dyn) ? 1.f : 0.f);
        if (l < nd) m1 = depotf;
        m2 = fmaxf(mk1b, (dem2 > dyn) ? 1.f : 0.f);
        if ((l + 64) < nd) m2 = depotf;
        if (g == 0){
            if (l == 0) out[(size_t)b*n_steps + s] = (float)bix;
            // shadow lse (logp OUTPUT only — fast-math safe, no feedback to actions)
            float tm = 1.0f - 2.0f*__builtin_amdgcn_rcpf(__expf(2.0f*bv*INV_D_CONST) + 1.0f);
            float Lm = tm * 10.0f * invtemp;
            float L1;
            if (m1o > 0.f) L1 = -1000000000.0f * invtemp;
            else {
                float t1 = 1.0f - 2.0f*__builtin_amdgcn_rcpf(__expf(2.0f*s1v*INV_D_CONST) + 1.0f);
                L1 = t1 * 10.0f * invtemp;
            }
            float e1 = __expf(L1 - Lm);
            float e2 = 0.f;
            if (hasB){
                float L2;
                if (m2o > 0.f) L2 = -1000000000.0f * invtemp;
                else {
                    float t2 = 1.0f - 2.0f*__builtin_amdgcn_rcpf(__expf(2.0f*s2v*INV_D_CONST) + 1.0f);
                    L2 = t2 * 10.0f * invtemp;
                }
                e2 = __expf(L2 - Lm);
            }
            float ss = wave_sum64(e1 + e2);
            if (keep_lp) logps += -__logf(ss);
        }
    }
    if (t == 0) out[(size_t)gridDim.x*n_steps + b] = logps;
}

extern "C" void kernel_launch(void* const* d_in, const int* in_sizes, int n_in,
                              void* d_out, int out_size, void* d_ws, size_t ws_size,
                              hipStream_t stream) {
    const float* enc     = (const float*)d_in[0];
    const float* pool    = (const float*)d_in[1];
    const float* capv    = (const float*)d_in[2];
    const float* demand  = (const float*)d_in[3];
    const float* fc_w    = (const float*)d_in[4];
    const float* fc1_w   = (const float*)d_in[5];
    const float* attn_w  = (const float*)d_in[6];
    const float* attn_k  = (const float*)d_in[7];
    const float* attn_v  = (const float*)d_in[8];
    const float* attn_fc = (const float*)d_in[9];
    const float* prob_k  = (const float*)d_in[10];
    const void*  p_nd    = d_in[12];
    const void*  p_temp  = d_in[13];

    int B = in_sizes[1] / D128;          // pool is (B, D)
    int n_steps = out_size / B - 1;      // out = B*n_steps actions + B logps
    int M = B * NT;

    float* ws    = (float*)d_ws;
    float* Wcat  = ws;                               // 128*512
    float* wlast = Wcat + 128*512;                   // 128
    float* pq    = wlast + 128;                      // B*128
    float* KVP   = pq + (size_t)B*D128;              // M*384
    float* QA    = KVP + (size_t)M*384;              // M*128

    prep_w2<<<129, 512, 0, stream>>>(fc_w, attn_w, prob_k, attn_fc, attn_k, attn_v, Wcat, wlast);
    prep_pq<<<B, 128, 0, stream>>>(pool, fc1_w, attn_w, pq);
    dim3 ggrid((M + 63)/64, 8);
    gemm_prep<<<ggrid, 256, 0, stream>>>(enc, Wcat, pq, M, KVP, QA);

    decode<<<B, TDEC, 0, stream>>>(QA, KVP, wlast, demand, capv, p_nd, p_temp,
                                   n_steps, (float*)d_out);
}

// Round 14
// 937.780 us; speedup vs baseline: 1.3966x; 1.3966x over previous
//
#include <hip/hip_runtime.h>

#define D128 128
#define NT 101
#define TDEC 512
#define PSTR 112            // padded p row: 4 quarters of 28 floats (16B aligned)
#define PVP 116             // VH inner (n) pitch, mult of 4 -> aligned b128
#define VGPP (16*PVP)       // per-head VH pitch = 1856 floats
#define LGB 832             // one LGH buffer: 8 waves x 104 (b32, consecutive-lane = conflict-free)

// ---- decode LDS layout (floats) ----
#define VH_OFF   0                       // [8][16 d][PVP n] V slices (n zero-padded)
#define P_OFF    (VH_OFF + 8*VGPP)       // 8 x PSTR
#define LGH_OFF  (P_OFF + 8*PSTR)        // 2 x 8 x 104 double-buffered logit partials
#define LDS_FLOATS (LGH_OFF + 2*LGB)     // 17408 floats = 69,632 B -> 2 WG/CU

#define INV_D_CONST 0.08838834764831845f
#define NEG_INF __int_as_float(0xff800000)

__device__ __forceinline__ int read_scalar_int(const void* p){
    unsigned u = *(const unsigned*)p;
    if (u < 1000000u) return (int)u;
    return (int)__uint_as_float(u);
}
__device__ __forceinline__ float read_scalar_float(const void* p){
    unsigned u = *(const unsigned*)p;
    if (u < 1000000u) return (float)(int)u;
    return __uint_as_float(u);
}

// ---- DPP cross-lane helpers (VALU pipe, no DS) — verified correct R10/R11/R12 ----
template<int C> __device__ __forceinline__ float dppf(float x){
    return __int_as_float(__builtin_amdgcn_update_dpp(
        __float_as_int(x), __float_as_int(x), C, 0xF, 0xF, false));
}
template<int C, int RM> __device__ __forceinline__ float dppmf(float idv, float x){
    return __int_as_float(__builtin_amdgcn_update_dpp(
        __float_as_int(idv), __float_as_int(x), C, RM, 0xF, false));
}
__device__ __forceinline__ float rdlf(float v, int lane){
    return __int_as_float(__builtin_amdgcn_readlane(__float_as_int(v), lane));
}
// Canonical wave64 reductions: 4 mirror stages (rows uniform), bcast15/31 merge.
__device__ __forceinline__ float wave_sum64(float v){
    v += dppf<0xB1>(v); v += dppf<0x4E>(v); v += dppf<0x141>(v); v += dppf<0x140>(v);
    v += dppmf<0x142,0xa>(0.f, v);
    v += dppmf<0x143,0x8>(0.f, v);
    return rdlf(v, 63);
}
__device__ __forceinline__ float wave_max64(float v){
    v = fmaxf(v, dppf<0xB1>(v)); v = fmaxf(v, dppf<0x4E>(v));
    v = fmaxf(v, dppf<0x141>(v)); v = fmaxf(v, dppf<0x140>(v));
    v = fmaxf(v, dppmf<0x142,0xa>(NEG_INF, v));
    v = fmaxf(v, dppmf<0x143,0x8>(NEG_INF, v));
    return rdlf(v, 63);
}

// ---------------- weight folding (unchanged) ----------------
__global__ __launch_bounds__(512) void prep_w2(
        const float* __restrict__ fc_w, const float* __restrict__ attn_w,
        const float* __restrict__ prob_k, const float* __restrict__ attn_fc,
        const float* __restrict__ attn_k, const float* __restrict__ attn_v,
        float* __restrict__ Wcat, float* __restrict__ wlast){
    int i = blockIdx.x, t = threadIdx.x;
    if (i < 128){
        if (t < 128){
            Wcat[i*512 + t] = attn_k[i*D128 + t];
        } else if (t < 256){
            int j = t - 128;
            Wcat[i*512 + 128 + j] = attn_v[i*D128 + j];
        } else if (t < 384){
            int j = t - 256; float acc = 0.f;
            for (int e = 0; e < D128; ++e) acc += prob_k[i*D128+e]*attn_fc[j*D128+e];
            Wcat[i*512 + 256 + j] = acc;
        } else {
            int j = t - 384; float acc = 0.f;
            for (int e = 0; e < D128; ++e) acc += fc_w[i*D128+e]*attn_w[e*D128+j];
            Wcat[i*512 + 384 + j] = acc;
        }
    } else if (t < 128){
        float acc = 0.f;
        for (int e = 0; e < D128; ++e) acc += fc_w[128*D128+e]*attn_w[e*D128+t];
        wlast[t] = acc;
    }
}

__global__ __launch_bounds__(128) void prep_pq(
        const float* __restrict__ pool, const float* __restrict__ fc1_w,
        const float* __restrict__ attn_w, float* __restrict__ pq){
    __shared__ float s1[128], s2[128];
    int b = blockIdx.x, t = threadIdx.x;
    s1[t] = pool[(size_t)b*D128 + t];
    __syncthreads();
    float a = 0.f;
    for (int i = 0; i < D128; ++i) a += s1[i]*fc1_w[i*D128 + t];
    s2[t] = a;
    __syncthreads();
    float a2 = 0.f;
    for (int i = 0; i < D128; ++i) a2 += s2[i]*attn_w[i*D128 + t];
    pq[(size_t)b*D128 + t] = a2;
}

__global__ __launch_bounds__(256) void gemm_prep(
        const float* __restrict__ enc, const float* __restrict__ Wcat,
        const float* __restrict__ pq, int M,
        float* __restrict__ KVP, float* __restrict__ QA){
    __shared__ float As[64*132];
    const int t = threadIdx.x;
    const int m0 = blockIdx.x * 64;
    const int cb0 = blockIdx.y * 64;
    for (int i = t; i < 64*32; i += 256){
        int row = i >> 5, c4 = (i & 31) << 2;
        float4 val = make_float4(0.f,0.f,0.f,0.f);
        if (m0 + row < M) val = *(const float4*)(enc + (size_t)(m0+row)*D128 + c4);
        *(float4*)&As[row*132 + c4] = val;
    }
    __syncthreads();
    const int tx = t & 15, ty = t >> 4;
    float acc[4][4];
    #pragma unroll
    for (int i = 0; i < 4; ++i)
        #pragma unroll
        for (int j = 0; j < 4; ++j) acc[i][j] = 0.f;
    const float* wp = Wcat + cb0 + tx*4;
    #pragma unroll 4
    for (int k = 0; k < 128; ++k){
        float4 bv = *(const float4*)(wp + (size_t)k*512);
        float a0 = As[(ty*4+0)*132 + k];
        float a1 = As[(ty*4+1)*132 + k];
        float a2 = As[(ty*4+2)*132 + k];
        float a3 = As[(ty*4+3)*132 + k];
        acc[0][0] += a0*bv.x; acc[0][1] += a0*bv.y; acc[0][2] += a0*bv.z; acc[0][3] += a0*bv.w;
        acc[1][0] += a1*bv.x; acc[1][1] += a1*bv.y; acc[1][2] += a1*bv.z; acc[1][3] += a1*bv.w;
        acc[2][0] += a2*bv.x; acc[2][1] += a2*bv.y; acc[2][2] += a2*bv.z; acc[2][3] += a2*bv.w;
        acc[3][0] += a3*bv.x; acc[3][1] += a3*bv.y; acc[3][2] += a3*bv.z; acc[3][3] += a3*bv.w;
    }
    #pragma unroll
    for (int rr = 0; rr < 4; ++rr){
        int m = m0 + ty*4 + rr;
        if (m >= M) continue;
        if (cb0 < 384){
            *(float4*)&KVP[(size_t)m*384 + cb0 + tx*4] =
                make_float4(acc[rr][0], acc[rr][1], acc[rr][2], acc[rr][3]);
        } else {
            int bb = m / NT;
            int c = cb0 - 384 + tx*4;
            float4 pv = *(const float4*)(pq + (size_t)bb*D128 + c);
            *(float4*)&QA[(size_t)m*D128 + c] =
                make_float4(acc[rr][0]+pv.x, acc[rr][1]+pv.y, acc[rr][2]+pv.z, acc[rr][3]+pv.w);
        }
    }
}

// ---------------- sequential decode: 8 waves per batch elem, ONE barrier/step ----------------
// R12 structure (VGPR=64, 2 WG/CU, VALU-bound ~90%) with two register-neutral cuts:
// LGH back to conflict-free [w*104+l] b32 layout; argmax via wave_max + ballot/ffs
// (SGPR-side index selection, frees the index-VGPR DPP chain).
__global__ __attribute__((amdgpu_flat_work_group_size(TDEC, TDEC)))
void decode(
    const float* __restrict__ QA, const float* __restrict__ KVP,
    const float* __restrict__ wlast, const float* __restrict__ demand,
    const float* __restrict__ capv, const void* p_nd, const void* p_temp,
    int n_steps, float* __restrict__ out)
{
    __shared__ float sm[LDS_FLOATS];
    const int b = blockIdx.x, t = threadIdx.x;
    const int l = t & 63, g = t >> 6;          // lane, wave (= head = dim-block)
    const int qq = l >> 4, d16 = l & 15;       // PV mapping
    const int nd = read_scalar_int(p_nd);
    const float temp = read_scalar_float(p_temp);
    const float invtemp = 1.0f / temp;         // host-scalar; logp path only
    const float capfull = capv[0];
    float dyn = capv[b];
    const long mb = (long)b * NT;
    const bool hasB = (l < NT - 64);           // second-row validity (l < 37)

    // ---- K rows (head g) for n = l, l+64 ----
    float k0[16], k1[16];
    {
        const float* kr = KVP + (mb + l)*384 + g*16;
        #pragma unroll
        for (int j4 = 0; j4 < 4; ++j4){
            float4 a = *(const float4*)(kr + j4*4);
            k0[j4*4+0]=a.x; k0[j4*4+1]=a.y; k0[j4*4+2]=a.z; k0[j4*4+3]=a.w;
        }
    }
    if (hasB){
        const float* kr = KVP + (mb + l + 64)*384 + g*16;
        #pragma unroll
        for (int j4 = 0; j4 < 4; ++j4){
            float4 a = *(const float4*)(kr + j4*4);
            k1[j4*4+0]=a.x; k1[j4*4+1]=a.y; k1[j4*4+2]=a.z; k1[j4*4+3]=a.w;
        }
    } else {
        #pragma unroll
        for (int j = 0; j < 16; ++j) k1[j] = 0.f;
    }
    float kwl1 = 0.f, kwl2 = 0.f;
    #pragma unroll
    for (int j = 0; j < 16; ++j){
        float w = wlast[g*16 + j];
        kwl1 += w*k0[j]; kwl2 += w*k1[j];
    }
    // ---- kp2 rows (dims 16g..16g+16) for n = l, l+64 ----
    float p2a[16], p2b[16];
    {
        const float* kr = KVP + (mb + l)*384 + 256 + g*16;
        #pragma unroll
        for (int j4 = 0; j4 < 4; ++j4){
            float4 a = *(const float4*)(kr + j4*4);
            p2a[j4*4+0]=a.x; p2a[j4*4+1]=a.y; p2a[j4*4+2]=a.z; p2a[j4*4+3]=a.w;
        }
    }
    if (hasB){
        const float* kr = KVP + (mb + l + 64)*384 + 256 + g*16;
        #pragma unroll
        for (int j4 = 0; j4 < 4; ++j4){
            float4 a = *(const float4*)(kr + j4*4);
            p2b[j4*4+0]=a.x; p2b[j4*4+1]=a.y; p2b[j4*4+2]=a.z; p2b[j4*4+3]=a.w;
        }
    } else {
        #pragma unroll
        for (int j = 0; j < 16; ++j) p2b[j] = 0.f;
    }
    // ---- demand + mask registers (redundant across waves) ----
    float dem1 = demand[mb + l];
    float dem2 = hasB ? demand[mb + l + 64] : 0.f;
    float mk1a = 0.f, mk1b = 0.f;
    float m1 = (l < nd) ? 1.f : ((dem1 > dyn) ? 1.f : 0.f);
    float m2 = ((l + 64) < nd) ? 1.f : ((dem2 > dyn) ? 1.f : 0.f);
    int served = 0; float logps = 0.f;

    // ---- stage VH[g][d][n] transposed (n zero-padded to PVP), P pads ----
    for (int i = t; i < 8*112*16; i += TDEC){
        int gg = i / 1792, r = i - gg*1792;
        int n = r >> 4, d = r & 15;            // d inner: coalesced global read
        sm[VH_OFF + gg*VGPP + d*PVP + n] =
            (n < NT) ? KVP[(mb + n)*384 + 128 + gg*16 + d] : 0.f;
    }
    for (int i = t; i < 8*PSTR; i += TDEC) sm[P_OFF + i] = 0.f;
    // initial q slice (index0 = 0): lanes 0-15 of each wave hold q[g*16 + l]
    float qreg = 0.f;
    if (l < 16) qreg = QA[mb*D128 + g*16 + l];
    __syncthreads();

    for (int s = 0; s < n_steps; ++s){
        // ==== P1: q via readlane, compat -> softmax -> PV (wave-internal) ====
        float qk1 = 0.f, qk2 = 0.f;
        #pragma unroll
        for (int j = 0; j < 16; ++j){
            float qj = rdlf(qreg, j);
            qk1 += qj*k0[j]; qk2 += qj*k1[j];
        }
        float c1 = 0.25f*(qk1 + dyn*kwl1);
        if (m1 > 0.f) c1 = -1000000000.0f;
        float c2 = -1000000000.0f;
        if (hasB){
            float a = 0.25f*(qk2 + dyn*kwl2);
            c2 = (m2 > 0.f) ? -1000000000.0f : a;
        }
        float mx = wave_max64(fmaxf(c1, c2));
        float p1 = __expf(c1 - mx);
        float p2v = hasB ? __expf(c2 - mx) : 0.f;
        float ls = wave_sum64(p1 + p2v);
        sm[P_OFF + g*PSTR + l] = p1;
        if (hasB) sm[P_OFF + g*PSTR + 64 + l] = p2v;
        // same-wave DS ordering: write->read needs no __syncthreads
        float acc = 0.f;
        {
            const float4* pp = (const float4*)&sm[P_OFF + g*PSTR + qq*28];
            const float4* vp = (const float4*)&sm[VH_OFF + g*VGPP + d16*PVP + qq*28];
            #pragma unroll
            for (int i4 = 0; i4 < 7; ++i4){
                float4 pv = pp[i4];
                float4 vv = vp[i4];
                acc += pv.x*vv.x + pv.y*vv.y + pv.z*vv.z + pv.w*vv.w;
            }
        }
        // butterfly: every lane ends with the full sum for its d16 column
        acc += __shfl_xor(acc, 16, 64);
        acc += __shfl_xor(acc, 32, 64);
        // ls is wave-uniform: Newton-refined reciprocal, 1 mul per lane
        float lr = __builtin_amdgcn_rcpf(ls);
        lr = lr * (2.0f - ls*lr);
        float o_own = acc * lr;                // lane j (j<16) holds o[16g + j]

        // ==== P2: logit partials via readlane(o_own) — no O LDS round-trip ====
        float lg1 = 0.f, lg2 = 0.f;
        #pragma unroll
        for (int j = 0; j < 16; ++j){
            float oj = rdlf(o_own, j);
            lg1 += oj*p2a[j]; lg2 += oj*p2b[j];
        }
        {
            float* lgp = &sm[LGH_OFF + (s & 1)*LGB + g*104];
            lgp[l] = lg1;
            if (hasB) lgp[64 + l] = lg2;
        }
        __syncthreads();                       // the ONE barrier per step

        // ==== F: redundant in every wave (each needs bix for its own q fetch) ====
        const float* lgb = &sm[LGH_OFF + (s & 1)*LGB];
        float s1v = 0.f;
        #pragma unroll
        for (int w = 0; w < 8; ++w) s1v += lgb[w*104 + l];
        float s2v = 0.f;
        if (hasB){
            #pragma unroll
            for (int w = 0; w < 8; ++w) s2v += lgb[w*104 + 64 + l];
        }
        float r1 = (m1 > 0.f) ? -3.0e38f : s1v;
        float r2 = hasB ? ((m2 > 0.f) ? -3.0e38f : s2v) : -3.3e38f;
        // ballot-argmax: max, then first matching lane (r1 block first = first-index-wins)
        float bv = wave_max64(fmaxf(r1, r2));
        unsigned long long b1 = __ballot(r1 == bv);
        int bix;
        if (b1){
            bix = __ffsll((long long)b1) - 1;
        } else {
            unsigned long long b2 = __ballot(r2 == bv);
            bix = 64 + __ffsll((long long)b2) - 1;
        }
        // issue next q slice load ASAP (latency hides under bookkeeping + skew)
        if (l < 16) qreg = QA[(mb + bix)*D128 + g*16 + l];
        // save pre-update state for wave0's shadow lse
        float m1o = m1, m2o = m2;
        bool keep_lp = (served < NT - 1);
        // bookkeeping (wave-uniform; readlane, no DS)
        float selv = (bix < 64) ? rdlf(dem1, bix) : rdlf(dem2, bix - 64);
        float vis  = (bix < 64) ? rdlf(mk1a, bix) : rdlf(mk1b, bix - 64);
        bool go = bix < nd;
        float dynN = go ? capfull : (dyn - selv);
        if (!go && vis == 0.f) served++;
        if (bix == l && l >= nd) mk1a = 1.f;
        if (hasB && bix == (l + 64)) mk1b = 1.f;
        bool done = served >= NT - nd;
        float depotf = (go && !done) ? 1.f : 0.f;
        dyn = dynN;
        m1 = fmaxf(mk1a, (dem1 > dyn) ? 1.f : 0.f);
        if (l < nd) m1 = depotf;
        m2 = fmaxf(mk1b, (dem2 > dyn) ? 1.f : 0.f);
        if ((l + 64) < nd) m2 = depotf;
        if (g == 0){
            if (l == 0) out[(size_t)b*n_steps + s] = (float)bix;
            // shadow lse (logp OUTPUT only — fast-math safe, no feedback to actions)
            float tm = 1.0f - 2.0f*__builtin_amdgcn_rcpf(__expf(2.0f*bv*INV_D_CONST) + 1.0f);
            float Lm = tm * 10.0f * invtemp;
            float L1;
            if (m1o > 0.f) L1 = -1000000000.0f * invtemp;
            else {
                float t1 = 1.0f - 2.0f*__builtin_amdgcn_rcpf(__expf(2.0f*s1v*INV_D_CONST) + 1.0f);
                L1 = t1 * 10.0f * invtemp;
            }
            float e1 = __expf(L1 - Lm);
            float e2 = 0.f;
            if (hasB){
                float L2;
                if (m2o > 0.f) L2 = -1000000000.0f * invtemp;
                else {
                    float t2 = 1.0f - 2.0f*__builtin_amdgcn_rcpf(__expf(2.0f*s2v*INV_D_CONST) + 1.0f);
                    L2 = t2 * 10.0f * invtemp;
                }
                e2 = __expf(L2 - Lm);
            }
            float ss = wave_sum64(e1 + e2);
            if (keep_lp) logps += -__logf(ss);
        }
    }
    if (t == 0) out[(size_t)gridDim.x*n_steps + b] = logps;
}

extern "C" void kernel_launch(void* const* d_in, const int* in_sizes, int n_in,
                              void* d_out, int out_size, void* d_ws, size_t ws_size,
                              hipStream_t stream) {
    const float* enc     = (const float*)d_in[0];
    const float* pool    = (const float*)d_in[1];
    const float* capv    = (const float*)d_in[2];
    const float* demand  = (const float*)d_in[3];
    const float* fc_w    = (const float*)d_in[4];
    const float* fc1_w   = (const float*)d_in[5];
    const float* attn_w  = (const float*)d_in[6];
    const float* attn_k  = (const float*)d_in[7];
    const float* attn_v  = (const float*)d_in[8];
    const float* attn_fc = (const float*)d_in[9];
    const float* prob_k  = (const float*)d_in[10];
    const void*  p_nd    = d_in[12];
    const void*  p_temp  = d_in[13];

    int B = in_sizes[1] / D128;          // pool is (B, D)
    int n_steps = out_size / B - 1;      // out = B*n_steps actions + B logps
    int M = B * NT;

    float* ws    = (float*)d_ws;
    float* Wcat  = ws;                               // 128*512
    float* wlast = Wcat + 128*512;                   // 128
    float* pq    = wlast + 128;                      // B*128
    float* KVP   = pq + (size_t)B*D128;              // M*384
    float* QA    = KVP + (size_t)M*384;              // M*128

    prep_w2<<<129, 512, 0, stream>>>(fc_w, attn_w, prob_k, attn_fc, attn_k, attn_v, Wcat, wlast);
    prep_pq<<<B, 128, 0, stream>>>(pool, fc1_w, attn_w, pq);
    dim3 ggrid((M + 63)/64, 8);
    gemm_prep<<<ggrid, 256, 0, stream>>>(enc, Wcat, pq, M, KVP, QA);

    decode<<<B, TDEC, 0, stream>>>(QA, KVP, wlast, demand, capv, p_nd, p_temp,
                                   n_steps, (float*)d_out);
}

// Round 15
// 891.267 us; speedup vs baseline: 1.4694x; 1.0522x over previous
//
#include <hip/hip_runtime.h>

#define D128 128
#define NT 101
#define TDEC 512
#define PSTR 112            // padded p row: 4 quarters of 28 floats (16B aligned)
#define PVP 116             // VH inner (n) pitch, mult of 4 -> aligned b128
#define VGPP (16*PVP)       // per-head VH pitch = 1856 floats
#define LGB 832             // one LGH buffer: 8 waves x 104 (b32, consecutive-lane = conflict-free)

// ---- decode LDS layout (floats) ----
#define VH_OFF   0                       // [8][16 d][PVP n] V slices (n zero-padded)
#define P_OFF    (VH_OFF + 8*VGPP)       // 8 x PSTR
#define LGH_OFF  (P_OFF + 8*PSTR)        // 2 x 8 x 104 double-buffered logit partials
#define LDS_FLOATS (LGH_OFF + 2*LGB)     // 17408 floats = 69,632 B -> 2 WG/CU

#define INV_D_CONST 0.08838834764831845f
#define NEG_INF __int_as_float(0xff800000)

__device__ __forceinline__ int read_scalar_int(const void* p){
    unsigned u = *(const unsigned*)p;
    if (u < 1000000u) return (int)u;
    return (int)__uint_as_float(u);
}
__device__ __forceinline__ float read_scalar_float(const void* p){
    unsigned u = *(const unsigned*)p;
    if (u < 1000000u) return (float)(int)u;
    return __uint_as_float(u);
}

// ---- DPP cross-lane helpers (VALU pipe, no DS) — verified correct R10-R14 ----
template<int C> __device__ __forceinline__ float dppf(float x){
    return __int_as_float(__builtin_amdgcn_update_dpp(
        __float_as_int(x), __float_as_int(x), C, 0xF, 0xF, false));
}
template<int C, int RM> __device__ __forceinline__ float dppmf(float idv, float x){
    return __int_as_float(__builtin_amdgcn_update_dpp(
        __float_as_int(idv), __float_as_int(x), C, RM, 0xF, false));
}
__device__ __forceinline__ float rdlf(float v, int lane){
    return __int_as_float(__builtin_amdgcn_readlane(__float_as_int(v), lane));
}
// Canonical wave64 reductions: 4 mirror stages (rows uniform), bcast15/31 merge.
__device__ __forceinline__ float wave_sum64(float v){
    v += dppf<0xB1>(v); v += dppf<0x4E>(v); v += dppf<0x141>(v); v += dppf<0x140>(v);
    v += dppmf<0x142,0xa>(0.f, v);
    v += dppmf<0x143,0x8>(0.f, v);
    return rdlf(v, 63);
}
__device__ __forceinline__ float wave_max64(float v){
    v = fmaxf(v, dppf<0xB1>(v)); v = fmaxf(v, dppf<0x4E>(v));
    v = fmaxf(v, dppf<0x141>(v)); v = fmaxf(v, dppf<0x140>(v));
    v = fmaxf(v, dppmf<0x142,0xa>(NEG_INF, v));
    v = fmaxf(v, dppmf<0x143,0x8>(NEG_INF, v));
    return rdlf(v, 63);
}

// ---------------- weight folding + pooled-q, fused (one launch) ----------------
// blocks 0..127: Wcat row i; block 128: wlast; blocks 129..129+B-1: pq[b]
__global__ __launch_bounds__(512) void prep_wpq(
        const float* __restrict__ fc_w, const float* __restrict__ attn_w,
        const float* __restrict__ prob_k, const float* __restrict__ attn_fc,
        const float* __restrict__ attn_k, const float* __restrict__ attn_v,
        const float* __restrict__ pool, const float* __restrict__ fc1_w,
        float* __restrict__ Wcat, float* __restrict__ wlast, float* __restrict__ pq){
    __shared__ float s1[128], s2[128];
    int i = blockIdx.x, t = threadIdx.x;
    if (i < 128){
        if (t < 128){
            Wcat[i*512 + t] = attn_k[i*D128 + t];
        } else if (t < 256){
            int j = t - 128;
            Wcat[i*512 + 128 + j] = attn_v[i*D128 + j];
        } else if (t < 384){
            int j = t - 256; float acc = 0.f;
            for (int e = 0; e < D128; ++e) acc += prob_k[i*D128+e]*attn_fc[j*D128+e];
            Wcat[i*512 + 256 + j] = acc;
        } else {
            int j = t - 384; float acc = 0.f;
            for (int e = 0; e < D128; ++e) acc += fc_w[i*D128+e]*attn_w[e*D128+j];
            Wcat[i*512 + 384 + j] = acc;
        }
    } else if (i == 128){
        if (t < 128){
            float acc = 0.f;
            for (int e = 0; e < D128; ++e) acc += fc_w[128*D128+e]*attn_w[e*D128+t];
            wlast[t] = acc;
        }
    } else {
        int b = i - 129;
        if (t < 128) s1[t] = pool[(size_t)b*D128 + t];
        __syncthreads();
        if (t < 128){
            float a = 0.f;
            for (int e = 0; e < D128; ++e) a += s1[e]*fc1_w[e*D128 + t];
            s2[t] = a;
        }
        __syncthreads();
        if (t < 128){
            float a2 = 0.f;
            for (int e = 0; e < D128; ++e) a2 += s2[e]*attn_w[e*D128 + t];
            pq[(size_t)b*D128 + t] = a2;
        }
    }
}

__global__ __launch_bounds__(256) void gemm_prep(
        const float* __restrict__ enc, const float* __restrict__ Wcat,
        const float* __restrict__ pq, int M,
        float* __restrict__ KVP, float* __restrict__ QA){
    __shared__ float As[64*132];
    const int t = threadIdx.x;
    const int m0 = blockIdx.x * 64;
    const int cb0 = blockIdx.y * 64;
    for (int i = t; i < 64*32; i += 256){
        int row = i >> 5, c4 = (i & 31) << 2;
        float4 val = make_float4(0.f,0.f,0.f,0.f);
        if (m0 + row < M) val = *(const float4*)(enc + (size_t)(m0+row)*D128 + c4);
        *(float4*)&As[row*132 + c4] = val;
    }
    __syncthreads();
    const int tx = t & 15, ty = t >> 4;
    float acc[4][4];
    #pragma unroll
    for (int i = 0; i < 4; ++i)
        #pragma unroll
        for (int j = 0; j < 4; ++j) acc[i][j] = 0.f;
    const float* wp = Wcat + cb0 + tx*4;
    #pragma unroll 4
    for (int k = 0; k < 128; ++k){
        float4 bv = *(const float4*)(wp + (size_t)k*512);
        float a0 = As[(ty*4+0)*132 + k];
        float a1 = As[(ty*4+1)*132 + k];
        float a2 = As[(ty*4+2)*132 + k];
        float a3 = As[(ty*4+3)*132 + k];
        acc[0][0] += a0*bv.x; acc[0][1] += a0*bv.y; acc[0][2] += a0*bv.z; acc[0][3] += a0*bv.w;
        acc[1][0] += a1*bv.x; acc[1][1] += a1*bv.y; acc[1][2] += a1*bv.z; acc[1][3] += a1*bv.w;
        acc[2][0] += a2*bv.x; acc[2][1] += a2*bv.y; acc[2][2] += a2*bv.z; acc[2][3] += a2*bv.w;
        acc[3][0] += a3*bv.x; acc[3][1] += a3*bv.y; acc[3][2] += a3*bv.z; acc[3][3] += a3*bv.w;
    }
    #pragma unroll
    for (int rr = 0; rr < 4; ++rr){
        int m = m0 + ty*4 + rr;
        if (m >= M) continue;
        if (cb0 < 384){
            *(float4*)&KVP[(size_t)m*384 + cb0 + tx*4] =
                make_float4(acc[rr][0], acc[rr][1], acc[rr][2], acc[rr][3]);
        } else {
            int bb = m / NT;
            int c = cb0 - 384 + tx*4;
            float4 pv = *(const float4*)(pq + (size_t)bb*D128 + c);
            *(float4*)&QA[(size_t)m*D128 + c] =
                make_float4(acc[rr][0]+pv.x, acc[rr][1]+pv.y, acc[rr][2]+pv.z, acc[rr][3]+pv.w);
        }
    }
}

// ---------------- sequential decode: 8 waves per batch elem, ONE barrier/step ----------------
// R14 structure (VGPR=64, 2 WG/CU, VALU-bound ~88%) minus the P1 softmax max-pass:
// logits are bounded (|c| << 88) so exp never overflows; masked -1e9 underflows to
// exactly 0. Softmax output is mathematically unchanged (exp(c)/sum vs exp(c-m)/sum).
__global__ __attribute__((amdgpu_flat_work_group_size(TDEC, TDEC)))
void decode(
    const float* __restrict__ QA, const float* __restrict__ KVP,
    const float* __restrict__ wlast, const float* __restrict__ demand,
    const float* __restrict__ capv, const void* p_nd, const void* p_temp,
    int n_steps, float* __restrict__ out)
{
    __shared__ float sm[LDS_FLOATS];
    const int b = blockIdx.x, t = threadIdx.x;
    const int l = t & 63, g = t >> 6;          // lane, wave (= head = dim-block)
    const int qq = l >> 4, d16 = l & 15;       // PV mapping
    const int nd = read_scalar_int(p_nd);
    const float temp = read_scalar_float(p_temp);
    const float invtemp = 1.0f / temp;         // host-scalar; logp path only
    const float capfull = capv[0];
    float dyn = capv[b];
    const long mb = (long)b * NT;
    const bool hasB = (l < NT - 64);           // second-row validity (l < 37)

    // ---- K rows (head g) for n = l, l+64 ----
    float k0[16], k1[16];
    {
        const float* kr = KVP + (mb + l)*384 + g*16;
        #pragma unroll
        for (int j4 = 0; j4 < 4; ++j4){
            float4 a = *(const float4*)(kr + j4*4);
            k0[j4*4+0]=a.x; k0[j4*4+1]=a.y; k0[j4*4+2]=a.z; k0[j4*4+3]=a.w;
        }
    }
    if (hasB){
        const float* kr = KVP + (mb + l + 64)*384 + g*16;
        #pragma unroll
        for (int j4 = 0; j4 < 4; ++j4){
            float4 a = *(const float4*)(kr + j4*4);
            k1[j4*4+0]=a.x; k1[j4*4+1]=a.y; k1[j4*4+2]=a.z; k1[j4*4+3]=a.w;
        }
    } else {
        #pragma unroll
        for (int j = 0; j < 16; ++j) k1[j] = 0.f;
    }
    float kwl1 = 0.f, kwl2 = 0.f;
    #pragma unroll
    for (int j = 0; j < 16; ++j){
        float w = wlast[g*16 + j];
        kwl1 += w*k0[j]; kwl2 += w*k1[j];
    }
    // ---- kp2 rows (dims 16g..16g+16) for n = l, l+64 ----
    float p2a[16], p2b[16];
    {
        const float* kr = KVP + (mb + l)*384 + 256 + g*16;
        #pragma unroll
        for (int j4 = 0; j4 < 4; ++j4){
            float4 a = *(const float4*)(kr + j4*4);
            p2a[j4*4+0]=a.x; p2a[j4*4+1]=a.y; p2a[j4*4+2]=a.z; p2a[j4*4+3]=a.w;
        }
    }
    if (hasB){
        const float* kr = KVP + (mb + l + 64)*384 + 256 + g*16;
        #pragma unroll
        for (int j4 = 0; j4 < 4; ++j4){
            float4 a = *(const float4*)(kr + j4*4);
            p2b[j4*4+0]=a.x; p2b[j4*4+1]=a.y; p2b[j4*4+2]=a.z; p2b[j4*4+3]=a.w;
        }
    } else {
        #pragma unroll
        for (int j = 0; j < 16; ++j) p2b[j] = 0.f;
    }
    // ---- demand + mask registers (redundant across waves) ----
    float dem1 = demand[mb + l];
    float dem2 = hasB ? demand[mb + l + 64] : 0.f;
    float mk1a = 0.f, mk1b = 0.f;
    float m1 = (l < nd) ? 1.f : ((dem1 > dyn) ? 1.f : 0.f);
    float m2 = ((l + 64) < nd) ? 1.f : ((dem2 > dyn) ? 1.f : 0.f);
    int served = 0; float logps = 0.f;

    // ---- stage VH[g][d][n] transposed (n zero-padded to PVP), P pads ----
    for (int i = t; i < 8*112*16; i += TDEC){
        int gg = i / 1792, r = i - gg*1792;
        int n = r >> 4, d = r & 15;            // d inner: coalesced global read
        sm[VH_OFF + gg*VGPP + d*PVP + n] =
            (n < NT) ? KVP[(mb + n)*384 + 128 + gg*16 + d] : 0.f;
    }
    for (int i = t; i < 8*PSTR; i += TDEC) sm[P_OFF + i] = 0.f;
    // initial q slice (index0 = 0): lanes 0-15 of each wave hold q[g*16 + l]
    float qreg = 0.f;
    if (l < 16) qreg = QA[mb*D128 + g*16 + l];
    __syncthreads();

    for (int s = 0; s < n_steps; ++s){
        // ==== P1: q via readlane, compat -> softmax (no max pass) -> PV ====
        float qk1 = 0.f, qk2 = 0.f;
        #pragma unroll
        for (int j = 0; j < 16; ++j){
            float qj = rdlf(qreg, j);
            qk1 += qj*k0[j]; qk2 += qj*k1[j];
        }
        float c1 = 0.25f*(qk1 + dyn*kwl1);
        if (m1 > 0.f) c1 = -1000000000.0f;
        float c2 = -1000000000.0f;
        if (hasB){
            float a = 0.25f*(qk2 + dyn*kwl2);
            c2 = (m2 > 0.f) ? -1000000000.0f : a;
        }
        // |c| <= ~20 for unmasked entries; masked -1e9 underflows to exactly 0.
        float p1 = __expf(c1);
        float p2v = hasB ? __expf(c2) : 0.f;
        float ls = wave_sum64(p1 + p2v);
        sm[P_OFF + g*PSTR + l] = p1;
        if (hasB) sm[P_OFF + g*PSTR + 64 + l] = p2v;
        // same-wave DS ordering: write->read needs no __syncthreads
        float acc = 0.f;
        {
            const float4* pp = (const float4*)&sm[P_OFF + g*PSTR + qq*28];
            const float4* vp = (const float4*)&sm[VH_OFF + g*VGPP + d16*PVP + qq*28];
            #pragma unroll
            for (int i4 = 0; i4 < 7; ++i4){
                float4 pv = pp[i4];
                float4 vv = vp[i4];
                acc += pv.x*vv.x + pv.y*vv.y + pv.z*vv.z + pv.w*vv.w;
            }
        }
        // butterfly: every lane ends with the full sum for its d16 column
        acc += __shfl_xor(acc, 16, 64);
        acc += __shfl_xor(acc, 32, 64);
        // ls is wave-uniform: Newton-refined reciprocal, 1 mul per lane
        float lr = __builtin_amdgcn_rcpf(ls);
        lr = lr * (2.0f - ls*lr);
        float o_own = acc * lr;                // lane j (j<16) holds o[16g + j]

        // ==== P2: logit partials via readlane(o_own) — no O LDS round-trip ====
        float lg1 = 0.f, lg2 = 0.f;
        #pragma unroll
        for (int j = 0; j < 16; ++j){
            float oj = rdlf(o_own, j);
            lg1 += oj*p2a[j]; lg2 += oj*p2b[j];
        }
        {
            float* lgp = &sm[LGH_OFF + (s & 1)*LGB + g*104];
            lgp[l] = lg1;
            if (hasB) lgp[64 + l] = lg2;
        }
        __syncthreads();                       // the ONE barrier per step

        // ==== F: redundant in every wave (each needs bix for its own q fetch) ====
        const float* lgb = &sm[LGH_OFF + (s & 1)*LGB];
        float s1v = 0.f;
        #pragma unroll
        for (int w = 0; w < 8; ++w) s1v += lgb[w*104 + l];
        float s2v = 0.f;
        if (hasB){
            #pragma unroll
            for (int w = 0; w < 8; ++w) s2v += lgb[w*104 + 64 + l];
        }
        float r1 = (m1 > 0.f) ? -3.0e38f : s1v;
        float r2 = hasB ? ((m2 > 0.f) ? -3.0e38f : s2v) : -3.3e38f;
        // ballot-argmax: max, then first matching lane (r1 block first = first-index-wins)
        float bv = wave_max64(fmaxf(r1, r2));
        unsigned long long b1 = __ballot(r1 == bv);
        int bix;
        if (b1){
            bix = __ffsll((long long)b1) - 1;
        } else {
            unsigned long long b2 = __ballot(r2 == bv);
            bix = 64 + __ffsll((long long)b2) - 1;
        }
        // issue next q slice load ASAP (latency hides under bookkeeping + skew)
        if (l < 16) qreg = QA[(mb + bix)*D128 + g*16 + l];
        // save pre-update state for wave0's shadow lse
        float m1o = m1, m2o = m2;
        bool keep_lp = (served < NT - 1);
        // bookkeeping (wave-uniform; readlane, no DS)
        float selv = (bix < 64) ? rdlf(dem1, bix) : rdlf(dem2, bix - 64);
        float vis  = (bix < 64) ? rdlf(mk1a, bix) : rdlf(mk1b, bix - 64);
        bool go = bix < nd;
        float dynN = go ? capfull : (dyn - selv);
        if (!go && vis == 0.f) served++;
        if (bix == l && l >= nd) mk1a = 1.f;
        if (hasB && bix == (l + 64)) mk1b = 1.f;
        bool done = served >= NT - nd;
        float depotf = (go && !done) ? 1.f : 0.f;
        dyn = dynN;
        m1 = fmaxf(mk1a, (dem1 > dyn) ? 1.f : 0.f);
        if (l < nd) m1 = depotf;
        m2 = fmaxf(mk1b, (dem2 > dyn) ? 1.f : 0.f);
        if ((l + 64) < nd) m2 = depotf;
        if (g == 0){
            if (l == 0) out[(size_t)b*n_steps + s] = (float)bix;
            // shadow lse (logp OUTPUT only — fast-math safe, no feedback to actions)
            float tm = 1.0f - 2.0f*__builtin_amdgcn_rcpf(__expf(2.0f*bv*INV_D_CONST) + 1.0f);
            float Lm = tm * 10.0f * invtemp;
            float L1;
            if (m1o > 0.f) L1 = -1000000000.0f * invtemp;
            else {
                float t1 = 1.0f - 2.0f*__builtin_amdgcn_rcpf(__expf(2.0f*s1v*INV_D_CONST) + 1.0f);
                L1 = t1 * 10.0f * invtemp;
            }
            float e1 = __expf(L1 - Lm);
            float e2 = 0.f;
            if (hasB){
                float L2;
                if (m2o > 0.f) L2 = -1000000000.0f * invtemp;
                else {
                    float t2 = 1.0f - 2.0f*__builtin_amdgcn_rcpf(__expf(2.0f*s2v*INV_D_CONST) + 1.0f);
                    L2 = t2 * 10.0f * invtemp;
                }
                e2 = __expf(L2 - Lm);
            }
            float ss = wave_sum64(e1 + e2);
            if (keep_lp) logps += -__logf(ss);
        }
    }
    if (t == 0) out[(size_t)gridDim.x*n_steps + b] = logps;
}

extern "C" void kernel_launch(void* const* d_in, const int* in_sizes, int n_in,
                              void* d_out, int out_size, void* d_ws, size_t ws_size,
                              hipStream_t stream) {
    const float* enc     = (const float*)d_in[0];
    const float* pool    = (const float*)d_in[1];
    const float* capv    = (const float*)d_in[2];
    const float* demand  = (const float*)d_in[3];
    const float* fc_w    = (const float*)d_in[4];
    const float* fc1_w   = (const float*)d_in[5];
    const float* attn_w  = (const float*)d_in[6];
    const float* attn_k  = (const float*)d_in[7];
    const float* attn_v  = (const float*)d_in[8];
    const float* attn_fc = (const float*)d_in[9];
    const float* prob_k  = (const float*)d_in[10];
    const void*  p_nd    = d_in[12];
    const void*  p_temp  = d_in[13];

    int B = in_sizes[1] / D128;          // pool is (B, D)
    int n_steps = out_size / B - 1;      // out = B*n_steps actions + B logps
    int M = B * NT;

    float* ws    = (float*)d_ws;
    float* Wcat  = ws;                               // 128*512
    float* wlast = Wcat + 128*512;                   // 128
    float* pq    = wlast + 128;                      // B*128
    float* KVP   = pq + (size_t)B*D128;              // M*384
    float* QA    = KVP + (size_t)M*384;              // M*128

    prep_wpq<<<129 + B, 512, 0, stream>>>(fc_w, attn_w, prob_k, attn_fc, attn_k, attn_v,
                                          pool, fc1_w, Wcat, wlast, pq);
    dim3 ggrid((M + 63)/64, 8);
    gemm_prep<<<ggrid, 256, 0, stream>>>(enc, Wcat, pq, M, KVP, QA);

    decode<<<B, TDEC, 0, stream>>>(QA, KVP, wlast, demand, capv, p_nd, p_temp,
                                   n_steps, (float*)d_out);
}

// Round 16
// 888.597 us; speedup vs baseline: 1.4739x; 1.0030x over previous
//
#include <hip/hip_runtime.h>

#define D128 128
#define NT 101
#define TDEC 512
#define PSTR 112            // padded p row: 4 quarters of 28 floats (16B aligned)
#define PVP 116             // VH inner (n) pitch, mult of 4 -> aligned b128
#define VGPP (16*PVP)       // per-head VH pitch = 1856 floats
#define LGB 832             // one LGH buffer: 8 waves x 104 (b32, consecutive-lane = conflict-free)

// ---- decode LDS layout (floats) ----
#define VH_OFF   0                       // [8][16 d][PVP n] V slices (n zero-padded)
#define P_OFF    (VH_OFF + 8*VGPP)       // 8 x PSTR
#define LGH_OFF  (P_OFF + 8*PSTR)        // 2 x 8 x 104 double-buffered logit partials
#define LDS_FLOATS (LGH_OFF + 2*LGB)     // 17408 floats = 69,632 B -> 2 WG/CU

#define INV_D_CONST 0.08838834764831845f
#define NEG_INF __int_as_float(0xff800000)

__device__ __forceinline__ int read_scalar_int(const void* p){
    unsigned u = *(const unsigned*)p;
    if (u < 1000000u) return (int)u;
    return (int)__uint_as_float(u);
}
__device__ __forceinline__ float read_scalar_float(const void* p){
    unsigned u = *(const unsigned*)p;
    if (u < 1000000u) return (float)(int)u;
    return __uint_as_float(u);
}

// ---- DPP cross-lane helpers (VALU pipe, no DS) — verified correct R10-R15 ----
template<int C> __device__ __forceinline__ float dppf(float x){
    return __int_as_float(__builtin_amdgcn_update_dpp(
        __float_as_int(x), __float_as_int(x), C, 0xF, 0xF, false));
}
template<int C, int RM> __device__ __forceinline__ float dppmf(float idv, float x){
    return __int_as_float(__builtin_amdgcn_update_dpp(
        __float_as_int(idv), __float_as_int(x), C, RM, 0xF, false));
}
__device__ __forceinline__ float rdlf(float v, int lane){
    return __int_as_float(__builtin_amdgcn_readlane(__float_as_int(v), lane));
}
// Canonical wave64 reductions: 4 mirror stages (rows uniform), bcast15/31 merge.
__device__ __forceinline__ float wave_sum64(float v){
    v += dppf<0xB1>(v); v += dppf<0x4E>(v); v += dppf<0x141>(v); v += dppf<0x140>(v);
    v += dppmf<0x142,0xa>(0.f, v);
    v += dppmf<0x143,0x8>(0.f, v);
    return rdlf(v, 63);
}
__device__ __forceinline__ float wave_max64(float v){
    v = fmaxf(v, dppf<0xB1>(v)); v = fmaxf(v, dppf<0x4E>(v));
    v = fmaxf(v, dppf<0x141>(v)); v = fmaxf(v, dppf<0x140>(v));
    v = fmaxf(v, dppmf<0x142,0xa>(NEG_INF, v));
    v = fmaxf(v, dppmf<0x143,0x8>(NEG_INF, v));
    return rdlf(v, 63);
}

// ---------------- weight folding + pooled-q, fused (one launch) ----------------
// blocks 0..127: Wcat row i; block 128: wlast; blocks 129..129+B-1: pq[b]
__global__ __launch_bounds__(512) void prep_wpq(
        const float* __restrict__ fc_w, const float* __restrict__ attn_w,
        const float* __restrict__ prob_k, const float* __restrict__ attn_fc,
        const float* __restrict__ attn_k, const float* __restrict__ attn_v,
        const float* __restrict__ pool, const float* __restrict__ fc1_w,
        float* __restrict__ Wcat, float* __restrict__ wlast, float* __restrict__ pq){
    __shared__ float s1[128], s2[128];
    int i = blockIdx.x, t = threadIdx.x;
    if (i < 128){
        if (t < 128){
            Wcat[i*512 + t] = attn_k[i*D128 + t];
        } else if (t < 256){
            int j = t - 128;
            Wcat[i*512 + 128 + j] = attn_v[i*D128 + j];
        } else if (t < 384){
            int j = t - 256; float acc = 0.f;
            for (int e = 0; e < D128; ++e) acc += prob_k[i*D128+e]*attn_fc[j*D128+e];
            Wcat[i*512 + 256 + j] = acc;
        } else {
            int j = t - 384; float acc = 0.f;
            for (int e = 0; e < D128; ++e) acc += fc_w[i*D128+e]*attn_w[e*D128+j];
            Wcat[i*512 + 384 + j] = acc;
        }
    } else if (i == 128){
        if (t < 128){
            float acc = 0.f;
            for (int e = 0; e < D128; ++e) acc += fc_w[128*D128+e]*attn_w[e*D128+t];
            wlast[t] = acc;
        }
    } else {
        int b = i - 129;
        if (t < 128) s1[t] = pool[(size_t)b*D128 + t];
        __syncthreads();
        if (t < 128){
            float a = 0.f;
            for (int e = 0; e < D128; ++e) a += s1[e]*fc1_w[e*D128 + t];
            s2[t] = a;
        }
        __syncthreads();
        if (t < 128){
            float a2 = 0.f;
            for (int e = 0; e < D128; ++e) a2 += s2[e]*attn_w[e*D128 + t];
            pq[(size_t)b*D128 + t] = a2;
        }
    }
}

// 64-row tile staged ONCE, then all 8 column-blocks computed in-loop (was grid.y=8
// re-staging enc 8x). Same per-output FMA order -> bitwise-identical KVP/QA.
__global__ __launch_bounds__(256) void gemm_prep(
        const float* __restrict__ enc, const float* __restrict__ Wcat,
        const float* __restrict__ pq, int M,
        float* __restrict__ KVP, float* __restrict__ QA){
    __shared__ float As[64*132];
    const int t = threadIdx.x;
    const int m0 = blockIdx.x * 64;
    for (int i = t; i < 64*32; i += 256){
        int row = i >> 5, c4 = (i & 31) << 2;
        float4 val = make_float4(0.f,0.f,0.f,0.f);
        if (m0 + row < M) val = *(const float4*)(enc + (size_t)(m0+row)*D128 + c4);
        *(float4*)&As[row*132 + c4] = val;
    }
    __syncthreads();
    const int tx = t & 15, ty = t >> 4;
    for (int cb = 0; cb < 8; ++cb){
        const int cb0 = cb * 64;
        float acc[4][4];
        #pragma unroll
        for (int i = 0; i < 4; ++i)
            #pragma unroll
            for (int j = 0; j < 4; ++j) acc[i][j] = 0.f;
        const float* wp = Wcat + cb0 + tx*4;
        #pragma unroll 4
        for (int k = 0; k < 128; ++k){
            float4 bv = *(const float4*)(wp + (size_t)k*512);
            float a0 = As[(ty*4+0)*132 + k];
            float a1 = As[(ty*4+1)*132 + k];
            float a2 = As[(ty*4+2)*132 + k];
            float a3 = As[(ty*4+3)*132 + k];
            acc[0][0] += a0*bv.x; acc[0][1] += a0*bv.y; acc[0][2] += a0*bv.z; acc[0][3] += a0*bv.w;
            acc[1][0] += a1*bv.x; acc[1][1] += a1*bv.y; acc[1][2] += a1*bv.z; acc[1][3] += a1*bv.w;
            acc[2][0] += a2*bv.x; acc[2][1] += a2*bv.y; acc[2][2] += a2*bv.z; acc[2][3] += a2*bv.w;
            acc[3][0] += a3*bv.x; acc[3][1] += a3*bv.y; acc[3][2] += a3*bv.z; acc[3][3] += a3*bv.w;
        }
        #pragma unroll
        for (int rr = 0; rr < 4; ++rr){
            int m = m0 + ty*4 + rr;
            if (m >= M) continue;
            if (cb0 < 384){
                *(float4*)&KVP[(size_t)m*384 + cb0 + tx*4] =
                    make_float4(acc[rr][0], acc[rr][1], acc[rr][2], acc[rr][3]);
            } else {
                int bb = m / NT;
                int c = cb0 - 384 + tx*4;
                float4 pv = *(const float4*)(pq + (size_t)bb*D128 + c);
                *(float4*)&QA[(size_t)m*D128 + c] =
                    make_float4(acc[rr][0]+pv.x, acc[rr][1]+pv.y, acc[rr][2]+pv.z, acc[rr][3]+pv.w);
            }
        }
    }
}

// ---------------- sequential decode: 8 waves per batch elem, ONE barrier/step ----------------
// R15 decode, byte-identical (VGPR=64, 2 WG/CU, VALU-issue-bound ~85%).
__global__ __attribute__((amdgpu_flat_work_group_size(TDEC, TDEC)))
void decode(
    const float* __restrict__ QA, const float* __restrict__ KVP,
    const float* __restrict__ wlast, const float* __restrict__ demand,
    const float* __restrict__ capv, const void* p_nd, const void* p_temp,
    int n_steps, float* __restrict__ out)
{
    __shared__ float sm[LDS_FLOATS];
    const int b = blockIdx.x, t = threadIdx.x;
    const int l = t & 63, g = t >> 6;          // lane, wave (= head = dim-block)
    const int qq = l >> 4, d16 = l & 15;       // PV mapping
    const int nd = read_scalar_int(p_nd);
    const float temp = read_scalar_float(p_temp);
    const float invtemp = 1.0f / temp;         // host-scalar; logp path only
    const float capfull = capv[0];
    float dyn = capv[b];
    const long mb = (long)b * NT;
    const bool hasB = (l < NT - 64);           // second-row validity (l < 37)

    // ---- K rows (head g) for n = l, l+64 ----
    float k0[16], k1[16];
    {
        const float* kr = KVP + (mb + l)*384 + g*16;
        #pragma unroll
        for (int j4 = 0; j4 < 4; ++j4){
            float4 a = *(const float4*)(kr + j4*4);
            k0[j4*4+0]=a.x; k0[j4*4+1]=a.y; k0[j4*4+2]=a.z; k0[j4*4+3]=a.w;
        }
    }
    if (hasB){
        const float* kr = KVP + (mb + l + 64)*384 + g*16;
        #pragma unroll
        for (int j4 = 0; j4 < 4; ++j4){
            float4 a = *(const float4*)(kr + j4*4);
            k1[j4*4+0]=a.x; k1[j4*4+1]=a.y; k1[j4*4+2]=a.z; k1[j4*4+3]=a.w;
        }
    } else {
        #pragma unroll
        for (int j = 0; j < 16; ++j) k1[j] = 0.f;
    }
    float kwl1 = 0.f, kwl2 = 0.f;
    #pragma unroll
    for (int j = 0; j < 16; ++j){
        float w = wlast[g*16 + j];
        kwl1 += w*k0[j]; kwl2 += w*k1[j];
    }
    // ---- kp2 rows (dims 16g..16g+16) for n = l, l+64 ----
    float p2a[16], p2b[16];
    {
        const float* kr = KVP + (mb + l)*384 + 256 + g*16;
        #pragma unroll
        for (int j4 = 0; j4 < 4; ++j4){
            float4 a = *(const float4*)(kr + j4*4);
            p2a[j4*4+0]=a.x; p2a[j4*4+1]=a.y; p2a[j4*4+2]=a.z; p2a[j4*4+3]=a.w;
        }
    }
    if (hasB){
        const float* kr = KVP + (mb + l + 64)*384 + 256 + g*16;
        #pragma unroll
        for (int j4 = 0; j4 < 4; ++j4){
            float4 a = *(const float4*)(kr + j4*4);
            p2b[j4*4+0]=a.x; p2b[j4*4+1]=a.y; p2b[j4*4+2]=a.z; p2b[j4*4+3]=a.w;
        }
    } else {
        #pragma unroll
        for (int j = 0; j < 16; ++j) p2b[j] = 0.f;
    }
    // ---- demand + mask registers (redundant across waves) ----
    float dem1 = demand[mb + l];
    float dem2 = hasB ? demand[mb + l + 64] : 0.f;
    float mk1a = 0.f, mk1b = 0.f;
    float m1 = (l < nd) ? 1.f : ((dem1 > dyn) ? 1.f : 0.f);
    float m2 = ((l + 64) < nd) ? 1.f : ((dem2 > dyn) ? 1.f : 0.f);
    int served = 0; float logps = 0.f;

    // ---- stage VH[g][d][n] transposed (n zero-padded to PVP), P pads ----
    for (int i = t; i < 8*112*16; i += TDEC){
        int gg = i / 1792, r = i - gg*1792;
        int n = r >> 4, d = r & 15;            // d inner: coalesced global read
        sm[VH_OFF + gg*VGPP + d*PVP + n] =
            (n < NT) ? KVP[(mb + n)*384 + 128 + gg*16 + d] : 0.f;
    }
    for (int i = t; i < 8*PSTR; i += TDEC) sm[P_OFF + i] = 0.f;
    // initial q slice (index0 = 0): lanes 0-15 of each wave hold q[g*16 + l]
    float qreg = 0.f;
    if (l < 16) qreg = QA[mb*D128 + g*16 + l];
    __syncthreads();

    for (int s = 0; s < n_steps; ++s){
        // ==== P1: q via readlane, compat -> softmax (no max pass) -> PV ====
        float qk1 = 0.f, qk2 = 0.f;
        #pragma unroll
        for (int j = 0; j < 16; ++j){
            float qj = rdlf(qreg, j);
            qk1 += qj*k0[j]; qk2 += qj*k1[j];
        }
        float c1 = 0.25f*(qk1 + dyn*kwl1);
        if (m1 > 0.f) c1 = -1000000000.0f;
        float c2 = -1000000000.0f;
        if (hasB){
            float a = 0.25f*(qk2 + dyn*kwl2);
            c2 = (m2 > 0.f) ? -1000000000.0f : a;
        }
        // |c| <= ~20 for unmasked entries; masked -1e9 underflows to exactly 0.
        float p1 = __expf(c1);
        float p2v = hasB ? __expf(c2) : 0.f;
        float ls = wave_sum64(p1 + p2v);
        sm[P_OFF + g*PSTR + l] = p1;
        if (hasB) sm[P_OFF + g*PSTR + 64 + l] = p2v;
        // same-wave DS ordering: write->read needs no __syncthreads
        float acc = 0.f;
        {
            const float4* pp = (const float4*)&sm[P_OFF + g*PSTR + qq*28];
            const float4* vp = (const float4*)&sm[VH_OFF + g*VGPP + d16*PVP + qq*28];
            #pragma unroll
            for (int i4 = 0; i4 < 7; ++i4){
                float4 pv = pp[i4];
                float4 vv = vp[i4];
                acc += pv.x*vv.x + pv.y*vv.y + pv.z*vv.z + pv.w*vv.w;
            }
        }
        // butterfly: every lane ends with the full sum for its d16 column
        acc += __shfl_xor(acc, 16, 64);
        acc += __shfl_xor(acc, 32, 64);
        // ls is wave-uniform: Newton-refined reciprocal, 1 mul per lane
        float lr = __builtin_amdgcn_rcpf(ls);
        lr = lr * (2.0f - ls*lr);
        float o_own = acc * lr;                // lane j (j<16) holds o[16g + j]

        // ==== P2: logit partials via readlane(o_own) — no O LDS round-trip ====
        float lg1 = 0.f, lg2 = 0.f;
        #pragma unroll
        for (int j = 0; j < 16; ++j){
            float oj = rdlf(o_own, j);
            lg1 += oj*p2a[j]; lg2 += oj*p2b[j];
        }
        {
            float* lgp = &sm[LGH_OFF + (s & 1)*LGB + g*104];
            lgp[l] = lg1;
            if (hasB) lgp[64 + l] = lg2;
        }
        __syncthreads();                       // the ONE barrier per step

        // ==== F: redundant in every wave (each needs bix for its own q fetch) ====
        const float* lgb = &sm[LGH_OFF + (s & 1)*LGB];
        float s1v = 0.f;
        #pragma unroll
        for (int w = 0; w < 8; ++w) s1v += lgb[w*104 + l];
        float s2v = 0.f;
        if (hasB){
            #pragma unroll
            for (int w = 0; w < 8; ++w) s2v += lgb[w*104 + 64 + l];
        }
        float r1 = (m1 > 0.f) ? -3.0e38f : s1v;
        float r2 = hasB ? ((m2 > 0.f) ? -3.0e38f : s2v) : -3.3e38f;
        // ballot-argmax: max, then first matching lane (r1 block first = first-index-wins)
        float bv = wave_max64(fmaxf(r1, r2));
        unsigned long long b1 = __ballot(r1 == bv);
        int bix;
        if (b1){
            bix = __ffsll((long long)b1) - 1;
        } else {
            unsigned long long b2 = __ballot(r2 == bv);
            bix = 64 + __ffsll((long long)b2) - 1;
        }
        // issue next q slice load ASAP (latency hides under bookkeeping + skew)
        if (l < 16) qreg = QA[(mb + bix)*D128 + g*16 + l];
        // save pre-update state for wave0's shadow lse
        float m1o = m1, m2o = m2;
        bool keep_lp = (served < NT - 1);
        // bookkeeping (wave-uniform; readlane, no DS)
        float selv = (bix < 64) ? rdlf(dem1, bix) : rdlf(dem2, bix - 64);
        float vis  = (bix < 64) ? rdlf(mk1a, bix) : rdlf(mk1b, bix - 64);
        bool go = bix < nd;
        float dynN = go ? capfull : (dyn - selv);
        if (!go && vis == 0.f) served++;
        if (bix == l && l >= nd) mk1a = 1.f;
        if (hasB && bix == (l + 64)) mk1b = 1.f;
        bool done = served >= NT - nd;
        float depotf = (go && !done) ? 1.f : 0.f;
        dyn = dynN;
        m1 = fmaxf(mk1a, (dem1 > dyn) ? 1.f : 0.f);
        if (l < nd) m1 = depotf;
        m2 = fmaxf(mk1b, (dem2 > dyn) ? 1.f : 0.f);
        if ((l + 64) < nd) m2 = depotf;
        if (g == 0){
            if (l == 0) out[(size_t)b*n_steps + s] = (float)bix;
            // shadow lse (logp OUTPUT only — fast-math safe, no feedback to actions)
            float tm = 1.0f - 2.0f*__builtin_amdgcn_rcpf(__expf(2.0f*bv*INV_D_CONST) + 1.0f);
            float Lm = tm * 10.0f * invtemp;
            float L1;
            if (m1o > 0.f) L1 = -1000000000.0f * invtemp;
            else {
                float t1 = 1.0f - 2.0f*__builtin_amdgcn_rcpf(__expf(2.0f*s1v*INV_D_CONST) + 1.0f);
                L1 = t1 * 10.0f * invtemp;
            }
            float e1 = __expf(L1 - Lm);
            float e2 = 0.f;
            if (hasB){
                float L2;
                if (m2o > 0.f) L2 = -1000000000.0f * invtemp;
                else {
                    float t2 = 1.0f - 2.0f*__builtin_amdgcn_rcpf(__expf(2.0f*s2v*INV_D_CONST) + 1.0f);
                    L2 = t2 * 10.0f * invtemp;
                }
                e2 = __expf(L2 - Lm);
            }
            float ss = wave_sum64(e1 + e2);
            if (keep_lp) logps += -__logf(ss);
        }
    }
    if (t == 0) out[(size_t)gridDim.x*n_steps + b] = logps;
}

extern "C" void kernel_launch(void* const* d_in, const int* in_sizes, int n_in,
                              void* d_out, int out_size, void* d_ws, size_t ws_size,
                              hipStream_t stream) {
    const float* enc     = (const float*)d_in[0];
    const float* pool    = (const float*)d_in[1];
    const float* capv    = (const float*)d_in[2];
    const float* demand  = (const float*)d_in[3];
    const float* fc_w    = (const float*)d_in[4];
    const float* fc1_w   = (const float*)d_in[5];
    const float* attn_w  = (const float*)d_in[6];
    const float* attn_k  = (const float*)d_in[7];
    const float* attn_v  = (const float*)d_in[8];
    const float* attn_fc = (const float*)d_in[9];
    const float* prob_k  = (const float*)d_in[10];
    const void*  p_nd    = d_in[12];
    const void*  p_temp  = d_in[13];

    int B = in_sizes[1] / D128;          // pool is (B, D)
    int n_steps = out_size / B - 1;      // out = B*n_steps actions + B logps
    int M = B * NT;

    float* ws    = (float*)d_ws;
    float* Wcat  = ws;                               // 128*512
    float* wlast = Wcat + 128*512;                   // 128
    float* pq    = wlast + 128;                      // B*128
    float* KVP   = pq + (size_t)B*D128;              // M*384
    float* QA    = KVP + (size_t)M*384;              // M*128

    prep_wpq<<<129 + B, 512, 0, stream>>>(fc_w, attn_w, prob_k, attn_fc, attn_k, attn_v,
                                          pool, fc1_w, Wcat, wlast, pq);
    gemm_prep<<<(M + 63)/64, 256, 0, stream>>>(enc, Wcat, pq, M, KVP, QA);

    decode<<<B, TDEC, 0, stream>>>(QA, KVP, wlast, demand, capv, p_nd, p_temp,
                                   n_steps, (float*)d_out);
}